// Round 12
// baseline (236.501 us; speedup 1.0000x reference)
//
#include <hip/hip_runtime.h>
#include <hip/hip_bf16.h>
#include <cstddef>

#define NBMAX 512     // max buckets (256 nodes each -> supports nN <= 131072)
#define BCAP 5120     // per-bucket edge capacity; mean ~4092, sigma ~64
#define BKCHUNK 1600  // max edges per bucket-sort block (1024 sort blocks -> 1563)

typedef unsigned short bf16t;
typedef __attribute__((ext_vector_type(8))) short short8;
typedef __attribute__((ext_vector_type(4))) float f32x4;

static __device__ __forceinline__ float2 up2(unsigned u) {
    return make_float2(__uint_as_float(u << 16), __uint_as_float(u & 0xffff0000u));
}
static __device__ __forceinline__ bf16t f2bf(float f) {
    unsigned u = __float_as_uint(f);
    u += 0x7fffu + ((u >> 16) & 1u);  // round-to-nearest-even (finite values)
    return (bf16t)(u >> 16);
}
static __device__ __forceinline__ unsigned pk2(float a, float b) {
    return (unsigned)f2bf(a) | ((unsigned)f2bf(b) << 16);
}

// ---------------- pass 1: LDS counting-sort of edges into receiver/sender buckets ----------------
// R entry = (r&255)<<24 | s ; S entry = s&255 (u8). Last 4 blocks do W2-fragment prep.
__global__ void k_bucket(const int* __restrict__ S, const int* __restrict__ R,
                         unsigned* __restrict__ bufR, unsigned char* __restrict__ bufS,
                         int* __restrict__ gCntR, int* __restrict__ gCntS,
                         const float* __restrict__ W2, bf16t* __restrict__ W2f,
                         int nE, int nB) {
    __shared__ int histR[NBMAX], lstR[NBMAX], baseR[NBMAX];
    __shared__ int histS[NBMAX], lstS[NBMAX], baseS[NBMAX];
    __shared__ int sm[256];
    __shared__ unsigned sortedR[BKCHUNK];
    __shared__ unsigned short bOfR[BKCHUNK];
    __shared__ unsigned char sortedS[BKCHUNK];
    __shared__ unsigned short bOfS[BKCHUNK];
    int t = threadIdx.x;
    int nSort = gridDim.x - 4;
    if (blockIdx.x >= nSort) {
        int tt = (blockIdx.x - nSort) * blockDim.x + t;
        if (tt < 1024) {
            int nt = tt >> 7, kh = (tt >> 6) & 1, lane = tt & 63;
            int n = nt * 16 + (lane & 15);
            int k0 = kh * 32 + (lane >> 4) * 8;
            uint4 p;
            p.x = pk2(W2[(k0 + 0) * 128 + n], W2[(k0 + 1) * 128 + n]);
            p.y = pk2(W2[(k0 + 2) * 128 + n], W2[(k0 + 3) * 128 + n]);
            p.z = pk2(W2[(k0 + 4) * 128 + n], W2[(k0 + 5) * 128 + n]);
            p.w = pk2(W2[(k0 + 6) * 128 + n], W2[(k0 + 7) * 128 + n]);
            ((uint4*)W2f)[tt] = p;
        }
        return;
    }
    for (int i = t; i < NBMAX; i += 256) { histR[i] = 0; histS[i] = 0; }
    __syncthreads();
    int chunk = (nE + nSort - 1) / nSort;
    int e0 = blockIdx.x * chunk;
    int e1 = min(e0 + chunk, nE);
    for (int e = e0 + t; e < e1; e += 256) {
        atomicAdd(&histR[R[e] >> 8], 1);
        atomicAdd(&histS[S[e] >> 8], 1);
    }
    __syncthreads();
    {
        int c0 = histR[2 * t], c1 = histR[2 * t + 1];
        int ps = c0 + c1;
        sm[t] = ps;
        __syncthreads();
        for (int off = 1; off < 256; off <<= 1) {
            int y = (t >= off) ? sm[t - off] : 0;
            __syncthreads();
            sm[t] += y;
            __syncthreads();
        }
        int ex = sm[t] - ps;
        lstR[2 * t] = ex;
        lstR[2 * t + 1] = ex + c0;
    }
    __syncthreads();
    {
        int c0 = histS[2 * t], c1 = histS[2 * t + 1];
        int ps = c0 + c1;
        sm[t] = ps;
        __syncthreads();
        for (int off = 1; off < 256; off <<= 1) {
            int y = (t >= off) ? sm[t - off] : 0;
            __syncthreads();
            sm[t] += y;
            __syncthreads();
        }
        int ex = sm[t] - ps;
        lstS[2 * t] = ex;
        lstS[2 * t + 1] = ex + c0;
    }
    __syncthreads();
    for (int i = t; i < nB; i += 256) {
        int cR = histR[i];
        baseR[i] = cR ? atomicAdd(&gCntR[i], cR) : 0;
        int cS = histS[i];
        baseS[i] = cS ? atomicAdd(&gCntS[i], cS) : 0;
    }
    for (int i = t; i < NBMAX; i += 256) { histR[i] = 0; histS[i] = 0; }  // reuse as cursors
    __syncthreads();
    for (int e = e0 + t; e < e1; e += 256) {
        int r = R[e], s = S[e];
        int br = r >> 8;
        int p = lstR[br] + atomicAdd(&histR[br], 1);
        sortedR[p] = ((unsigned)(r & 255) << 24) | (unsigned)s;
        bOfR[p] = (unsigned short)br;
        int bs = s >> 8;
        int p2 = lstS[bs] + atomicAdd(&histS[bs], 1);
        sortedS[p2] = (unsigned char)(s & 255);
        bOfS[p2] = (unsigned short)bs;
    }
    __syncthreads();
    int cnt = e1 - e0;
    for (int i = t; i < cnt; i += 256) {
        int b = bOfR[i];
        int slot = baseR[b] + (i - lstR[b]);
        if (slot < BCAP) bufR[(size_t)b * BCAP + slot] = sortedR[i];
        int b2 = bOfS[i];
        int slot2 = baseS[b2] + (i - lstS[b2]);
        if (slot2 < BCAP) bufS[(size_t)b2 * BCAP + slot2] = sortedS[i];
    }
}

// ---------------- pass 2: grid 2*nB — blocks [0,nB) receivers, [nB,2nB) senders ----------------
__global__ void k_pass2(const unsigned* __restrict__ bufR, const unsigned char* __restrict__ bufS,
                        const int* __restrict__ gCntR, const int* __restrict__ gCntS,
                        const float* __restrict__ x,
                        int* __restrict__ csr, int* __restrict__ cur, int* __restrict__ degR,
                        float* __restrict__ inv_r, float* __restrict__ inv_s,
                        bf16t* __restrict__ xs, int nN, int nB) {
    __shared__ int hist[256], incl[256], curs[256];
    __shared__ int sm[256];
    __shared__ int gex[NBMAX];
    int t = threadIdx.x;
    if (blockIdx.x >= nB) {
        // ---- sender part: out-degree -> inv_s + xs prep (bf16) ----
        int b = blockIdx.x - nB;
        hist[t] = 0;
        __syncthreads();
        int cntS = gCntS[b];
        const unsigned char* bufs = bufS + (size_t)b * BCAP;
        for (int i = t; i < cntS; i += 256) atomicAdd(&hist[bufs[i]], 1);
        __syncthreads();
        int n = (b << 8) + t;
        if (n < nN) {
            float is = rsqrtf(fmaxf((float)hist[t], 1.f));
            inv_s[n] = is;
            float w[9];
#pragma unroll
            for (int k = 0; k < 9; k++) w[k] = x[(size_t)n * 9 + k] * is;
            uint4 pa, pb;
            pa.x = pk2(w[0], w[1]); pa.y = pk2(w[2], w[3]);
            pa.z = pk2(w[4], w[5]); pa.w = pk2(w[6], w[7]);
            pb.x = pk2(w[8], is);   pb.y = 0; pb.z = 0; pb.w = 0;
            uint4* o = (uint4*)(xs + (size_t)n * 16);
            o[0] = pa;
            o[1] = pb;
        }
        return;
    }
    // ---- receiver part: CSR + degR/cur/inv_r ----
    int b = blockIdx.x;
    {
        int c0 = (2 * t < nB) ? gCntR[2 * t] : 0;
        int c1 = (2 * t + 1 < nB) ? gCntR[2 * t + 1] : 0;
        int ps = c0 + c1;
        sm[t] = ps;
        __syncthreads();
        for (int off = 1; off < 256; off <<= 1) {
            int y = (t >= off) ? sm[t - off] : 0;
            __syncthreads();
            sm[t] += y;
            __syncthreads();
        }
        int ex = sm[t] - ps;
        gex[2 * t] = ex;
        gex[2 * t + 1] = ex + c0;
    }
    hist[t] = 0; curs[t] = 0;
    __syncthreads();
    int gb = gex[b];
    int cnt = gCntR[b];
    const unsigned* buf = bufR + (size_t)b * BCAP;
    for (int i = t; i < cnt; i += 256) atomicAdd(&hist[buf[i] >> 24], 1);
    __syncthreads();
    int v = hist[t];
    sm[t] = v;
    __syncthreads();
    for (int off = 1; off < 256; off <<= 1) {
        int y = (t >= off) ? sm[t - off] : 0;
        __syncthreads();
        sm[t] += y;
        __syncthreads();
    }
    incl[t] = sm[t];  // inclusive scan of bin counts
    __syncthreads();
    int n = (b << 8) + t;
    if (n < nN) {
        degR[n] = v;
        cur[n] = gb + incl[t];  // end offset (consumers use cur-deg)
        inv_r[n] = rsqrtf(fmaxf((float)v, 1.f));
    }
    for (int i = t; i < cnt; i += 256) {
        unsigned p = buf[i];
        int rl = p >> 24;
        int s = p & 0xFFFFFF;
        int pos = gb + (incl[rl] - hist[rl]) + atomicAdd(&curs[rl], 1);
        csr[pos] = s;  // contiguous ~16KB window per block
    }
}

// ---------------- fused layer-1 agg + dense: quarter-wave per node, 16 edges in flight ----------------
__global__ void k_h1f(const unsigned* __restrict__ xs32, const float* __restrict__ W1,
                      const float* __restrict__ b1,
                      const int* __restrict__ csr, const int* __restrict__ cur,
                      const int* __restrict__ degR, const float* __restrict__ inv_r,
                      const float* __restrict__ inv_s,
                      bf16t* __restrict__ h1s, float* __restrict__ warr, int nN) {
    __shared__ float Wl[9 * 64];
    __shared__ float bl[64];
    for (int i = threadIdx.x; i < 9 * 64; i += blockDim.x) Wl[i] = W1[i];
    if (threadIdx.x < 64) bl[threadIdx.x] = b1[threadIdx.x];
    __syncthreads();
    int lane = threadIdx.x & 63;
    int wave = threadIdx.x >> 6;
    int n = blockIdx.x * 16 + wave * 4 + (lane >> 4);
    int ql = lane & 15;
    int g = ql >> 2;
    int f2 = ql & 3;
    int nc = min(n, nN - 1);
    int deg = degR[nc];
    int st = cur[nc] - deg;
    float4 A0 = {0.f, 0.f, 0.f, 0.f}, A1 = A0, A2 = A0, A3 = A0;
    int i = 0;
    for (; i + 16 <= deg; i += 16) {
        int ea = csr[st + i + g];
        int eb = csr[st + i + 4 + g];
        int ec = csr[st + i + 8 + g];
        int ed = csr[st + i + 12 + g];
        uint2 u0 = *(const uint2*)(xs32 + (size_t)ea * 8 + f2 * 2);
        uint2 u1 = *(const uint2*)(xs32 + (size_t)eb * 8 + f2 * 2);
        uint2 u2 = *(const uint2*)(xs32 + (size_t)ec * 8 + f2 * 2);
        uint2 u3 = *(const uint2*)(xs32 + (size_t)ed * 8 + f2 * 2);
        float2 a = up2(u0.x), b = up2(u0.y);
        A0.x += a.x; A0.y += a.y; A0.z += b.x; A0.w += b.y;
        a = up2(u1.x); b = up2(u1.y);
        A1.x += a.x; A1.y += a.y; A1.z += b.x; A1.w += b.y;
        a = up2(u2.x); b = up2(u2.y);
        A2.x += a.x; A2.y += a.y; A2.z += b.x; A2.w += b.y;
        a = up2(u3.x); b = up2(u3.y);
        A3.x += a.x; A3.y += a.y; A3.z += b.x; A3.w += b.y;
    }
    for (; i + 4 <= deg; i += 4) {
        int ea = csr[st + i + g];
        uint2 u0 = *(const uint2*)(xs32 + (size_t)ea * 8 + f2 * 2);
        float2 a = up2(u0.x), b = up2(u0.y);
        A0.x += a.x; A0.y += a.y; A0.z += b.x; A0.w += b.y;
    }
    if (g < deg - i) {
        int ea = csr[st + i + g];
        uint2 u0 = *(const uint2*)(xs32 + (size_t)ea * 8 + f2 * 2);
        float2 a = up2(u0.x), b = up2(u0.y);
        A1.x += a.x; A1.y += a.y; A1.z += b.x; A1.w += b.y;
    }
    float4 vq = {(A0.x + A1.x) + (A2.x + A3.x), (A0.y + A1.y) + (A2.y + A3.y),
                 (A0.z + A1.z) + (A2.z + A3.z), (A0.w + A1.w) + (A2.w + A3.w)};
    vq.x += __shfl_xor(vq.x, 4); vq.y += __shfl_xor(vq.y, 4);
    vq.z += __shfl_xor(vq.z, 4); vq.w += __shfl_xor(vq.w, 4);
    vq.x += __shfl_xor(vq.x, 8); vq.y += __shfl_xor(vq.y, 8);
    vq.z += __shfl_xor(vq.z, 8); vq.w += __shfl_xor(vq.w, 8);
    int base = lane & 48;
    float xv[9];
    xv[0] = __shfl(vq.x, base + 0); xv[1] = __shfl(vq.y, base + 0);
    xv[2] = __shfl(vq.z, base + 0); xv[3] = __shfl(vq.w, base + 0);
    xv[4] = __shfl(vq.x, base + 1); xv[5] = __shfl(vq.y, base + 1);
    xv[6] = __shfl(vq.z, base + 1); xv[7] = __shfl(vq.w, base + 1);
    xv[8] = __shfl(vq.x, base + 2);
    float w = __shfl(vq.y, base + 2);
    float ir = inv_r[nc];
    float is = inv_s[nc];
    int c0 = ql * 4;
    float acc[4];
#pragma unroll
    for (int j = 0; j < 4; j++) acc[j] = w * bl[c0 + j];
#pragma unroll
    for (int k = 0; k < 9; k++) {
        float4 wv = *(const float4*)(Wl + k * 64 + c0);
        acc[0] += xv[k] * wv.x;
        acc[1] += xv[k] * wv.y;
        acc[2] += xv[k] * wv.z;
        acc[3] += xv[k] * wv.w;
    }
    if (n < nN) {
        float v0 = fmaxf(acc[0] * ir, 0.f) * is;
        float v1 = fmaxf(acc[1] * ir, 0.f) * is;
        float v2 = fmaxf(acc[2] * ir, 0.f) * is;
        float v3 = fmaxf(acc[3] * ir, 0.f) * is;
        uint2 pv;
        pv.x = pk2(v0, v1);
        pv.y = pk2(v2, v3);
        *(uint2*)(h1s + (size_t)n * 64 + c0) = pv;
        if (ql == 0) warr[n] = w;
    }
}

// ---------------- fused layer-2 gather + MFMA 64->128->2 ----------------
__global__ void k_l2f(const unsigned* __restrict__ h32, const bf16t* __restrict__ W2f,
                      const float* __restrict__ b2, const float* __restrict__ W3,
                      const float* __restrict__ inv_r, const float* __restrict__ inv_s,
                      const float* __restrict__ warr,
                      const int* __restrict__ csr, const int* __restrict__ cur,
                      const int* __restrict__ degR,
                      float* __restrict__ t, float* __restrict__ dout, int outSize, int nN) {
    __shared__ unsigned zl[64 * 36];  // 64 rows x 144B
    if (blockIdx.x == 0 && threadIdx.x < outSize) dout[threadIdx.x] = 0.f;
    int lane = threadIdx.x & 63;
    int wave = threadIdx.x >> 6;
    int n0w = blockIdx.x * 64 + wave * 16;
    int q = lane >> 4;
    int ql = lane & 15;
    for (int j = 0; j < 16; j++) {
        int nc = min(n0w + j, nN - 1);
        int deg = degR[nc];
        int st = cur[nc] - deg;
        float4 A0 = {0.f, 0.f, 0.f, 0.f}, A1 = A0, A2 = A0, A3 = A0;
        int i = 0;
        for (; i + 16 <= deg; i += 16) {
            int ea = csr[st + i + q];
            int eb = csr[st + i + 4 + q];
            int ec = csr[st + i + 8 + q];
            int ed = csr[st + i + 12 + q];
            uint2 u0 = *(const uint2*)(h32 + (size_t)ea * 32 + ql * 2);
            uint2 u1 = *(const uint2*)(h32 + (size_t)eb * 32 + ql * 2);
            uint2 u2 = *(const uint2*)(h32 + (size_t)ec * 32 + ql * 2);
            uint2 u3 = *(const uint2*)(h32 + (size_t)ed * 32 + ql * 2);
            float2 a = up2(u0.x), bb = up2(u0.y);
            A0.x += a.x; A0.y += a.y; A0.z += bb.x; A0.w += bb.y;
            a = up2(u1.x); bb = up2(u1.y);
            A1.x += a.x; A1.y += a.y; A1.z += bb.x; A1.w += bb.y;
            a = up2(u2.x); bb = up2(u2.y);
            A2.x += a.x; A2.y += a.y; A2.z += bb.x; A2.w += bb.y;
            a = up2(u3.x); bb = up2(u3.y);
            A3.x += a.x; A3.y += a.y; A3.z += bb.x; A3.w += bb.y;
        }
        for (; i + 4 <= deg; i += 4) {
            int ea = csr[st + i + q];
            uint2 u0 = *(const uint2*)(h32 + (size_t)ea * 32 + ql * 2);
            float2 a = up2(u0.x), bb = up2(u0.y);
            A0.x += a.x; A0.y += a.y; A0.z += bb.x; A0.w += bb.y;
        }
        if (q < deg - i) {
            int ea = csr[st + i + q];
            uint2 u0 = *(const uint2*)(h32 + (size_t)ea * 32 + ql * 2);
            float2 a = up2(u0.x), bb = up2(u0.y);
            A1.x += a.x; A1.y += a.y; A1.z += bb.x; A1.w += bb.y;
        }
        float4 v = {(A0.x + A1.x) + (A2.x + A3.x), (A0.y + A1.y) + (A2.y + A3.y),
                    (A0.z + A1.z) + (A2.z + A3.z), (A0.w + A1.w) + (A2.w + A3.w)};
        v.x += __shfl_xor(v.x, 16); v.y += __shfl_xor(v.y, 16);
        v.z += __shfl_xor(v.z, 16); v.w += __shfl_xor(v.w, 16);
        v.x += __shfl_xor(v.x, 32); v.y += __shfl_xor(v.y, 32);
        v.z += __shfl_xor(v.z, 32); v.w += __shfl_xor(v.w, 32);
        if (q == 0) {
            uint2 pv;
            pv.x = pk2(v.x, v.y);
            pv.y = pk2(v.z, v.w);
            *(uint2*)(zl + (wave * 16 + j) * 36 + ql * 2) = pv;
        }
    }
    int m = ql;
    float bc[8], w30[8], w31[8];
#pragma unroll
    for (int nt = 0; nt < 8; nt++) {
        int col = nt * 16 + m;
        bc[nt] = b2[col];
        w30[nt] = W3[col * 2 + 0];
        w31[nt] = W3[col * 2 + 1];
    }
    int row = wave * 16 + m;
    short8 afr0 = *(const short8*)(zl + row * 36 + q * 4);
    short8 afr1 = *(const short8*)(zl + row * 36 + 16 + q * 4);
    float w4[4], ir4[4], is4[4];
#pragma unroll
    for (int reg = 0; reg < 4; reg++) {
        int nr = min(n0w + q * 4 + reg, nN - 1);
        w4[reg] = warr[nr];
        ir4[reg] = inv_r[nr];
        is4[reg] = inv_s[nr];
    }
    float p0[4] = {0.f, 0.f, 0.f, 0.f}, p1[4] = {0.f, 0.f, 0.f, 0.f};
#pragma unroll
    for (int nt = 0; nt < 8; nt++) {
        short8 b0 = *(const short8*)(W2f + ((size_t)(nt * 2 + 0) * 64 + lane) * 8);
        short8 b1 = *(const short8*)(W2f + ((size_t)(nt * 2 + 1) * 64 + lane) * 8);
        f32x4 acc = {0.f, 0.f, 0.f, 0.f};
        acc = __builtin_amdgcn_mfma_f32_16x16x32_bf16(afr0, b0, acc, 0, 0, 0);
        acc = __builtin_amdgcn_mfma_f32_16x16x32_bf16(afr1, b1, acc, 0, 0, 0);
#pragma unroll
        for (int reg = 0; reg < 4; reg++) {
            float h = fmaxf((acc[reg] + w4[reg] * bc[nt]) * ir4[reg], 0.f) * is4[reg];
            p0[reg] += h * w30[nt];
            p1[reg] += h * w31[nt];
        }
    }
#pragma unroll
    for (int mask = 1; mask < 16; mask <<= 1) {
#pragma unroll
        for (int reg = 0; reg < 4; reg++) {
            p0[reg] += __shfl_xor(p0[reg], mask);
            p1[reg] += __shfl_xor(p1[reg], mask);
        }
    }
    if (m == 0) {
#pragma unroll
        for (int reg = 0; reg < 4; reg++) {
            int nr = n0w + q * 4 + reg;
            if (nr < nN) *(float2*)(t + (size_t)nr * 2) = make_float2(p0[reg], p1[reg]);
        }
    }
}

// ---------------- pooling (node-parallel over CSR), unroll x4 ----------------
__global__ void k_poolg(const float* __restrict__ t, const float* __restrict__ inv_r,
                        const float* __restrict__ warr, const float* __restrict__ b3,
                        const int* __restrict__ csr, const int* __restrict__ cur,
                        const int* __restrict__ degR, const int* __restrict__ batch,
                        float* out, int nN, int outSize) {
    __shared__ float sm[256];
    for (int i = threadIdx.x; i < 256; i += blockDim.x) sm[i] = 0.f;
    __syncthreads();
    float b30 = b3[0], b31 = b3[1];
    int n = blockIdx.x * blockDim.x + threadIdx.x;
    if (n < nN) {
        int deg = degR[n];
        int st = cur[n] - deg;
        float a0 = 0.f, a1 = 0.f, c0 = 0.f, c1 = 0.f;
        float d0 = 0.f, d1 = 0.f, e0 = 0.f, e1 = 0.f;
        int i = 0;
        for (; i + 4 <= deg; i += 4) {
            int sa = csr[st + i], sb = csr[st + i + 1];
            int sc = csr[st + i + 2], sd = csr[st + i + 3];
            float2 va = ((const float2*)t)[sa];
            float2 vb = ((const float2*)t)[sb];
            float2 vc = ((const float2*)t)[sc];
            float2 vd = ((const float2*)t)[sd];
            a0 += va.x; a1 += va.y;
            c0 += vb.x; c1 += vb.y;
            d0 += vc.x; d1 += vc.y;
            e0 += vd.x; e1 += vd.y;
        }
        for (; i < deg; i++) {
            float2 va = ((const float2*)t)[csr[st + i]];
            a0 += va.x; a1 += va.y;
        }
        float ir = inv_r[n];
        float wb = warr[n] * ir;
        int g = batch[n];
        atomicAdd(&sm[2 * g + 0], ((a0 + c0) + (d0 + e0)) * ir + wb * b30);
        atomicAdd(&sm[2 * g + 1], ((a1 + c1) + (d1 + e1)) * ir + wb * b31);
    }
    __syncthreads();
    for (int i = threadIdx.x; i < outSize; i += blockDim.x) atomicAdd(&out[i], sm[i]);
}

extern "C" void kernel_launch(void* const* d_in, const int* in_sizes, int n_in,
                              void* d_out, int out_size, void* d_ws, size_t ws_size,
                              hipStream_t stream) {
    const float* x     = (const float*)d_in[0];
    const int*   S     = (const int*)d_in[1];
    const int*   R     = (const int*)d_in[2];
    const int*   batch = (const int*)d_in[3];
    const float* W1 = (const float*)d_in[5];
    const float* b1 = (const float*)d_in[6];
    const float* W2 = (const float*)d_in[7];
    const float* b2 = (const float*)d_in[8];
    const float* W3 = (const float*)d_in[9];
    const float* b3 = (const float*)d_in[10];

    int nN = in_sizes[0] / 9;
    int nE = in_sizes[1];
    int nB = (nN + 255) / 256;  // 256-node buckets; requires nB <= NBMAX

    char* ws = (char*)d_ws;
    int*   cur   = (int*)ws;                          // nN
    int*   degR  = cur + nN;                          // nN
    float* inv_s = (float*)(degR + nN);               // nN
    float* inv_r = inv_s + nN;                        // nN
    float* warr  = inv_r + nN;                        // nN
    int*   gCntR = (int*)(warr + nN);                 // NBMAX
    int*   gCntS = gCntR + NBMAX;                     // NBMAX
    int*   csr   = gCntS + NBMAX;                     // nE
    bf16t* xs    = (bf16t*)(csr + nE);                // nN*16 bf16 (3.2 MB)
    bf16t* W2f   = xs + (size_t)nN * 16;              // 8192 bf16 (16 KB)
    char*  regA  = (char*)(W2f + 8192);
    // aliasing (bufR/bufS dead after k_pass2; h1s written by k_h1f afterwards)
    unsigned*      bufR = (unsigned*)regA;                                // NBMAX*BCAP*4 = 10.5 MB
    unsigned char* bufS = (unsigned char*)(bufR + (size_t)NBMAX * BCAP);  // NBMAX*BCAP   = 2.6 MB
    bf16t* h1s = (bf16t*)regA;                        // nN*64 bf16 (12.8 MB)
    float* t   = (float*)(regA + (size_t)NBMAX * BCAP * 5);  // nN*2 fp32 (past both regions)

    const int B = 256;

    // ---- build: bucket sort (1024 sort blocks + 4 W2-prep blocks), then combined pass 2 ----
    hipMemsetAsync(gCntR, 0, 2 * NBMAX * 4, stream);
    k_bucket<<<1028, B, 0, stream>>>(S, R, bufR, bufS, gCntR, gCntS, W2, W2f, nE, nB);
    k_pass2<<<2 * nB, B, 0, stream>>>(bufR, bufS, gCntR, gCntS, x, csr, cur, degR,
                                      inv_r, inv_s, xs, nN, nB);

    // ---- layer 1: fused gather + 9->64 dense ----
    k_h1f<<<(nN + 15) / 16, B, 0, stream>>>((const unsigned*)xs, W1, b1, csr, cur, degR,
                                            inv_r, inv_s, h1s, warr, nN);

    // ---- layers 2+3: fused gather + MFMA 64->128->2 (also zeroes d_out) ----
    k_l2f<<<(nN + 63) / 64, B, 0, stream>>>((const unsigned*)h1s, W2f, b2, W3,
                                            inv_r, inv_s, warr, csr, cur, degR,
                                            t, (float*)d_out, out_size, nN);

    // ---- fused layer-3 aggregation + bias + pooling ----
    k_poolg<<<(nN + B - 1) / B, B, 0, stream>>>(t, inv_r, warr, b3, csr, cur, degR, batch,
                                                (float*)d_out, nN, out_size);
}

// Round 13
// 229.612 us; speedup vs baseline: 1.0300x; 1.0300x over previous
//
#include <hip/hip_runtime.h>
#include <hip/hip_bf16.h>
#include <cstddef>

#define NBMAX 512     // max buckets (256 nodes each -> supports nN <= 131072)
#define BCAP 5120     // per-bucket edge capacity; mean ~4092, sigma ~64
#define BKCHUNK 3200  // max edges per bucket-sort block (512 sort blocks -> 3125)

typedef unsigned short bf16t;
typedef __attribute__((ext_vector_type(8))) short short8;
typedef __attribute__((ext_vector_type(4))) float f32x4;

static __device__ __forceinline__ float2 up2(unsigned u) {
    return make_float2(__uint_as_float(u << 16), __uint_as_float(u & 0xffff0000u));
}
static __device__ __forceinline__ bf16t f2bf(float f) {
    unsigned u = __float_as_uint(f);
    u += 0x7fffu + ((u >> 16) & 1u);  // round-to-nearest-even (finite values)
    return (bf16t)(u >> 16);
}
static __device__ __forceinline__ unsigned pk2(float a, float b) {
    return (unsigned)f2bf(a) | ((unsigned)f2bf(b) << 16);
}

// ---------------- pass 1: LDS counting-sort of edges into receiver/sender buckets ----------------
// R entry = (r&255)<<24 | s ; S entry = s&255 (u8). Last 4 blocks do W2-fragment prep.
// 512 sort blocks: ~3125 edges/block over 391 buckets -> ~8-edge coalesced flush runs.
__global__ void k_bucket(const int* __restrict__ S, const int* __restrict__ R,
                         unsigned* __restrict__ bufR, unsigned char* __restrict__ bufS,
                         int* __restrict__ gCntR, int* __restrict__ gCntS,
                         const float* __restrict__ W2, bf16t* __restrict__ W2f,
                         int nE, int nB) {
    __shared__ int histR[NBMAX], lstR[NBMAX], baseR[NBMAX];
    __shared__ int histS[NBMAX], lstS[NBMAX], baseS[NBMAX];
    __shared__ int sm[256];
    __shared__ unsigned sortedR[BKCHUNK];
    __shared__ unsigned short bOfR[BKCHUNK];
    __shared__ unsigned char sortedS[BKCHUNK];
    __shared__ unsigned short bOfS[BKCHUNK];
    int t = threadIdx.x;
    int nSort = gridDim.x - 4;
    if (blockIdx.x >= nSort) {
        // W2 -> MFMA B^T fragment prep: n = nt*16+(lane&15), k = kh*32+(lane>>4)*8+j
        int tt = (blockIdx.x - nSort) * blockDim.x + t;
        if (tt < 1024) {
            int nt = tt >> 7, kh = (tt >> 6) & 1, lane = tt & 63;
            int n = nt * 16 + (lane & 15);
            int k0 = kh * 32 + (lane >> 4) * 8;
            uint4 p;
            p.x = pk2(W2[(k0 + 0) * 128 + n], W2[(k0 + 1) * 128 + n]);
            p.y = pk2(W2[(k0 + 2) * 128 + n], W2[(k0 + 3) * 128 + n]);
            p.z = pk2(W2[(k0 + 4) * 128 + n], W2[(k0 + 5) * 128 + n]);
            p.w = pk2(W2[(k0 + 6) * 128 + n], W2[(k0 + 7) * 128 + n]);
            ((uint4*)W2f)[tt] = p;
        }
        return;
    }
    for (int i = t; i < NBMAX; i += 256) { histR[i] = 0; histS[i] = 0; }
    __syncthreads();
    int chunk = (nE + nSort - 1) / nSort;
    int e0 = blockIdx.x * chunk;
    int e1 = min(e0 + chunk, nE);
    for (int e = e0 + t; e < e1; e += 256) {
        atomicAdd(&histR[R[e] >> 8], 1);
        atomicAdd(&histS[S[e] >> 8], 1);
    }
    __syncthreads();
    {
        int c0 = histR[2 * t], c1 = histR[2 * t + 1];
        int ps = c0 + c1;
        sm[t] = ps;
        __syncthreads();
        for (int off = 1; off < 256; off <<= 1) {
            int y = (t >= off) ? sm[t - off] : 0;
            __syncthreads();
            sm[t] += y;
            __syncthreads();
        }
        int ex = sm[t] - ps;
        lstR[2 * t] = ex;
        lstR[2 * t + 1] = ex + c0;
    }
    __syncthreads();
    {
        int c0 = histS[2 * t], c1 = histS[2 * t + 1];
        int ps = c0 + c1;
        sm[t] = ps;
        __syncthreads();
        for (int off = 1; off < 256; off <<= 1) {
            int y = (t >= off) ? sm[t - off] : 0;
            __syncthreads();
            sm[t] += y;
            __syncthreads();
        }
        int ex = sm[t] - ps;
        lstS[2 * t] = ex;
        lstS[2 * t + 1] = ex + c0;
    }
    __syncthreads();
    for (int i = t; i < nB; i += 256) {
        int cR = histR[i];
        baseR[i] = cR ? atomicAdd(&gCntR[i], cR) : 0;
        int cS = histS[i];
        baseS[i] = cS ? atomicAdd(&gCntS[i], cS) : 0;
    }
    for (int i = t; i < NBMAX; i += 256) { histR[i] = 0; histS[i] = 0; }  // reuse as cursors
    __syncthreads();
    for (int e = e0 + t; e < e1; e += 256) {
        int r = R[e], s = S[e];
        int br = r >> 8;
        int p = lstR[br] + atomicAdd(&histR[br], 1);
        sortedR[p] = ((unsigned)(r & 255) << 24) | (unsigned)s;
        bOfR[p] = (unsigned short)br;
        int bs = s >> 8;
        int p2 = lstS[bs] + atomicAdd(&histS[bs], 1);
        sortedS[p2] = (unsigned char)(s & 255);
        bOfS[p2] = (unsigned short)bs;
    }
    __syncthreads();
    int cnt = e1 - e0;
    for (int i = t; i < cnt; i += 256) {
        int b = bOfR[i];
        int slot = baseR[b] + (i - lstR[b]);
        if (slot < BCAP) bufR[(size_t)b * BCAP + slot] = sortedR[i];
        int b2 = bOfS[i];
        int slot2 = baseS[b2] + (i - lstS[b2]);
        if (slot2 < BCAP) bufS[(size_t)b2 * BCAP + slot2] = sortedS[i];
    }
}

// ---------------- pass 2: per-bucket CSR + degR/inv_r + inv_s + xs prep (256 nodes/bucket) ----------------
__global__ void k_pass2(const unsigned* __restrict__ bufR, const unsigned char* __restrict__ bufS,
                        const int* __restrict__ gCntR, const int* __restrict__ gCntS,
                        const float* __restrict__ x,
                        int* __restrict__ csr, int* __restrict__ cur, int* __restrict__ degR,
                        float* __restrict__ inv_r, float* __restrict__ inv_s,
                        bf16t* __restrict__ xs, int nN, int nB) {
    __shared__ int hist[256], incl[256], curs[256], histS[256];
    __shared__ int sm[256];
    __shared__ int gex[NBMAX];
    int t = threadIdx.x;
    int b = blockIdx.x;
    // inline exclusive scan of gCntR -> global edge base per bucket
    {
        int c0 = (2 * t < nB) ? gCntR[2 * t] : 0;
        int c1 = (2 * t + 1 < nB) ? gCntR[2 * t + 1] : 0;
        int ps = c0 + c1;
        sm[t] = ps;
        __syncthreads();
        for (int off = 1; off < 256; off <<= 1) {
            int y = (t >= off) ? sm[t - off] : 0;
            __syncthreads();
            sm[t] += y;
            __syncthreads();
        }
        int ex = sm[t] - ps;
        gex[2 * t] = ex;
        gex[2 * t + 1] = ex + c0;
    }
    hist[t] = 0; curs[t] = 0; histS[t] = 0;
    __syncthreads();
    int gb = gex[b];
    int cnt = gCntR[b];
    const unsigned* buf = bufR + (size_t)b * BCAP;
    for (int i = t; i < cnt; i += 256) atomicAdd(&hist[buf[i] >> 24], 1);
    __syncthreads();
    int v = hist[t];
    sm[t] = v;
    __syncthreads();
    for (int off = 1; off < 256; off <<= 1) {
        int y = (t >= off) ? sm[t - off] : 0;
        __syncthreads();
        sm[t] += y;
        __syncthreads();
    }
    incl[t] = sm[t];  // inclusive scan of bin counts
    __syncthreads();
    int n0 = b << 8;
    int n = n0 + t;
    if (n < nN) {
        degR[n] = v;
        cur[n] = gb + incl[t];  // end offset (consumers use cur-deg)
        inv_r[n] = rsqrtf(fmaxf((float)v, 1.f));
    }
    for (int i = t; i < cnt; i += 256) {
        unsigned p = buf[i];
        int rl = p >> 24;
        int s = p & 0xFFFFFF;
        int pos = gb + (incl[rl] - hist[rl]) + atomicAdd(&curs[rl], 1);
        csr[pos] = s;  // contiguous ~16KB window per block
    }
    // ---- sender part: out-degree -> inv_s + xs prep (bf16) ----
    int cntS = gCntS[b];
    const unsigned char* bufs = bufS + (size_t)b * BCAP;
    for (int i = t; i < cntS; i += 256) atomicAdd(&histS[bufs[i]], 1);
    __syncthreads();
    if (n < nN) {
        float is = rsqrtf(fmaxf((float)histS[t], 1.f));
        inv_s[n] = is;
        float w[9];
#pragma unroll
        for (int k = 0; k < 9; k++) w[k] = x[(size_t)n * 9 + k] * is;
        uint4 pa, pb;
        pa.x = pk2(w[0], w[1]); pa.y = pk2(w[2], w[3]);
        pa.z = pk2(w[4], w[5]); pa.w = pk2(w[6], w[7]);
        pb.x = pk2(w[8], is);   pb.y = 0; pb.z = 0; pb.w = 0;
        uint4* o = (uint4*)(xs + (size_t)n * 16);
        o[0] = pa;
        o[1] = pb;
    }
}

// ---------------- fused layer-1 agg + dense: quarter-wave per node, 16 edges in flight ----------------
__global__ void k_h1f(const unsigned* __restrict__ xs32, const float* __restrict__ W1,
                      const float* __restrict__ b1,
                      const int* __restrict__ csr, const int* __restrict__ cur,
                      const int* __restrict__ degR, const float* __restrict__ inv_r,
                      const float* __restrict__ inv_s,
                      bf16t* __restrict__ h1s, float* __restrict__ warr, int nN) {
    __shared__ float Wl[9 * 64];
    __shared__ float bl[64];
    for (int i = threadIdx.x; i < 9 * 64; i += blockDim.x) Wl[i] = W1[i];
    if (threadIdx.x < 64) bl[threadIdx.x] = b1[threadIdx.x];
    __syncthreads();
    int lane = threadIdx.x & 63;
    int wave = threadIdx.x >> 6;
    int n = blockIdx.x * 16 + wave * 4 + (lane >> 4);
    int ql = lane & 15;
    int g = ql >> 2;      // edge slot within quarter (4 edges in parallel)
    int f2 = ql & 3;      // uint2 index into the 32B xs row
    int nc = min(n, nN - 1);
    int deg = degR[nc];
    int st = cur[nc] - deg;
    float4 A0 = {0.f, 0.f, 0.f, 0.f}, A1 = A0, A2 = A0, A3 = A0;
    int i = 0;
    for (; i + 16 <= deg; i += 16) {
        int ea = csr[st + i + g];
        int eb = csr[st + i + 4 + g];
        int ec = csr[st + i + 8 + g];
        int ed = csr[st + i + 12 + g];
        uint2 u0 = *(const uint2*)(xs32 + (size_t)ea * 8 + f2 * 2);
        uint2 u1 = *(const uint2*)(xs32 + (size_t)eb * 8 + f2 * 2);
        uint2 u2 = *(const uint2*)(xs32 + (size_t)ec * 8 + f2 * 2);
        uint2 u3 = *(const uint2*)(xs32 + (size_t)ed * 8 + f2 * 2);
        float2 a = up2(u0.x), b = up2(u0.y);
        A0.x += a.x; A0.y += a.y; A0.z += b.x; A0.w += b.y;
        a = up2(u1.x); b = up2(u1.y);
        A1.x += a.x; A1.y += a.y; A1.z += b.x; A1.w += b.y;
        a = up2(u2.x); b = up2(u2.y);
        A2.x += a.x; A2.y += a.y; A2.z += b.x; A2.w += b.y;
        a = up2(u3.x); b = up2(u3.y);
        A3.x += a.x; A3.y += a.y; A3.z += b.x; A3.w += b.y;
    }
    for (; i + 4 <= deg; i += 4) {
        int ea = csr[st + i + g];
        uint2 u0 = *(const uint2*)(xs32 + (size_t)ea * 8 + f2 * 2);
        float2 a = up2(u0.x), b = up2(u0.y);
        A0.x += a.x; A0.y += a.y; A0.z += b.x; A0.w += b.y;
    }
    if (g < deg - i) {
        int ea = csr[st + i + g];
        uint2 u0 = *(const uint2*)(xs32 + (size_t)ea * 8 + f2 * 2);
        float2 a = up2(u0.x), b = up2(u0.y);
        A1.x += a.x; A1.y += a.y; A1.z += b.x; A1.w += b.y;
    }
    float4 vq = {(A0.x + A1.x) + (A2.x + A3.x), (A0.y + A1.y) + (A2.y + A3.y),
                 (A0.z + A1.z) + (A2.z + A3.z), (A0.w + A1.w) + (A2.w + A3.w)};
    vq.x += __shfl_xor(vq.x, 4); vq.y += __shfl_xor(vq.y, 4);
    vq.z += __shfl_xor(vq.z, 4); vq.w += __shfl_xor(vq.w, 4);
    vq.x += __shfl_xor(vq.x, 8); vq.y += __shfl_xor(vq.y, 8);
    vq.z += __shfl_xor(vq.z, 8); vq.w += __shfl_xor(vq.w, 8);
    int base = lane & 48;
    float xv[9];
    xv[0] = __shfl(vq.x, base + 0); xv[1] = __shfl(vq.y, base + 0);
    xv[2] = __shfl(vq.z, base + 0); xv[3] = __shfl(vq.w, base + 0);
    xv[4] = __shfl(vq.x, base + 1); xv[5] = __shfl(vq.y, base + 1);
    xv[6] = __shfl(vq.z, base + 1); xv[7] = __shfl(vq.w, base + 1);
    xv[8] = __shfl(vq.x, base + 2);
    float w = __shfl(vq.y, base + 2);
    float ir = inv_r[nc];
    float is = inv_s[nc];
    int c0 = ql * 4;
    float acc[4];
#pragma unroll
    for (int j = 0; j < 4; j++) acc[j] = w * bl[c0 + j];
#pragma unroll
    for (int k = 0; k < 9; k++) {
        float4 wv = *(const float4*)(Wl + k * 64 + c0);
        acc[0] += xv[k] * wv.x;
        acc[1] += xv[k] * wv.y;
        acc[2] += xv[k] * wv.z;
        acc[3] += xv[k] * wv.w;
    }
    if (n < nN) {
        float v0 = fmaxf(acc[0] * ir, 0.f) * is;
        float v1 = fmaxf(acc[1] * ir, 0.f) * is;
        float v2 = fmaxf(acc[2] * ir, 0.f) * is;
        float v3 = fmaxf(acc[3] * ir, 0.f) * is;
        uint2 pv;
        pv.x = pk2(v0, v1);
        pv.y = pk2(v2, v3);
        *(uint2*)(h1s + (size_t)n * 64 + c0) = pv;
        if (ql == 0) warr[n] = w;
    }
}

// ---------------- fused layer-2 gather + MFMA 64->128->2 ----------------
// block = 64 nodes (4 waves x 16). Phase 1: wave gathers its 16 nodes into LDS rows
// (stride 36 dwords; rows wave-private). Phase 2: MFMA 16x16x32 with A from LDS,
// epilogue bias/relu/scales in C-layout, dot W3, xor-reduce, write t.
__global__ void k_l2f(const unsigned* __restrict__ h32, const bf16t* __restrict__ W2f,
                      const float* __restrict__ b2, const float* __restrict__ W3,
                      const float* __restrict__ inv_r, const float* __restrict__ inv_s,
                      const float* __restrict__ warr,
                      const int* __restrict__ csr, const int* __restrict__ cur,
                      const int* __restrict__ degR,
                      float* __restrict__ t, float* __restrict__ dout, int outSize, int nN) {
    __shared__ float b2l[128];
    __shared__ float W3l[256];
    __shared__ unsigned zl[64 * 36];  // 64 rows x 144B
    for (int i = threadIdx.x; i < 128; i += blockDim.x) b2l[i] = b2[i];
    for (int i = threadIdx.x; i < 256; i += blockDim.x) W3l[i] = W3[i];
    if (blockIdx.x == 0 && threadIdx.x < outSize) dout[threadIdx.x] = 0.f;  // before k_poolg
    int lane = threadIdx.x & 63;
    int wave = threadIdx.x >> 6;
    int n0w = blockIdx.x * 64 + wave * 16;
    int q = lane >> 4;    // edge slot (4 edges in parallel)
    int ql = lane & 15;   // uint2 index into the 128B row
    for (int j = 0; j < 16; j++) {
        int nc = min(n0w + j, nN - 1);
        int deg = degR[nc];
        int st = cur[nc] - deg;
        float4 A0 = {0.f, 0.f, 0.f, 0.f}, A1 = A0, A2 = A0, A3 = A0;
        int i = 0;
        for (; i + 16 <= deg; i += 16) {
            int ea = csr[st + i + q];
            int eb = csr[st + i + 4 + q];
            int ec = csr[st + i + 8 + q];
            int ed = csr[st + i + 12 + q];
            uint2 u0 = *(const uint2*)(h32 + (size_t)ea * 32 + ql * 2);
            uint2 u1 = *(const uint2*)(h32 + (size_t)eb * 32 + ql * 2);
            uint2 u2 = *(const uint2*)(h32 + (size_t)ec * 32 + ql * 2);
            uint2 u3 = *(const uint2*)(h32 + (size_t)ed * 32 + ql * 2);
            float2 a = up2(u0.x), bb = up2(u0.y);
            A0.x += a.x; A0.y += a.y; A0.z += bb.x; A0.w += bb.y;
            a = up2(u1.x); bb = up2(u1.y);
            A1.x += a.x; A1.y += a.y; A1.z += bb.x; A1.w += bb.y;
            a = up2(u2.x); bb = up2(u2.y);
            A2.x += a.x; A2.y += a.y; A2.z += bb.x; A2.w += bb.y;
            a = up2(u3.x); bb = up2(u3.y);
            A3.x += a.x; A3.y += a.y; A3.z += bb.x; A3.w += bb.y;
        }
        for (; i + 4 <= deg; i += 4) {
            int ea = csr[st + i + q];
            uint2 u0 = *(const uint2*)(h32 + (size_t)ea * 32 + ql * 2);
            float2 a = up2(u0.x), bb = up2(u0.y);
            A0.x += a.x; A0.y += a.y; A0.z += bb.x; A0.w += bb.y;
        }
        if (q < deg - i) {
            int ea = csr[st + i + q];
            uint2 u0 = *(const uint2*)(h32 + (size_t)ea * 32 + ql * 2);
            float2 a = up2(u0.x), bb = up2(u0.y);
            A1.x += a.x; A1.y += a.y; A1.z += bb.x; A1.w += bb.y;
        }
        float4 v = {(A0.x + A1.x) + (A2.x + A3.x), (A0.y + A1.y) + (A2.y + A3.y),
                    (A0.z + A1.z) + (A2.z + A3.z), (A0.w + A1.w) + (A2.w + A3.w)};
        v.x += __shfl_xor(v.x, 16); v.y += __shfl_xor(v.y, 16);
        v.z += __shfl_xor(v.z, 16); v.w += __shfl_xor(v.w, 16);
        v.x += __shfl_xor(v.x, 32); v.y += __shfl_xor(v.y, 32);
        v.z += __shfl_xor(v.z, 32); v.w += __shfl_xor(v.w, 32);
        if (q == 0) {
            uint2 pv;
            pv.x = pk2(v.x, v.y);
            pv.y = pk2(v.z, v.w);
            *(uint2*)(zl + (wave * 16 + j) * 36 + ql * 2) = pv;
        }
    }
    __syncthreads();  // for b2l/W3l (z rows are wave-private)
    int m = ql;
    int row = wave * 16 + m;
    short8 afr0 = *(const short8*)(zl + row * 36 + q * 4);
    short8 afr1 = *(const short8*)(zl + row * 36 + 16 + q * 4);
    float w4[4], ir4[4], is4[4];
#pragma unroll
    for (int reg = 0; reg < 4; reg++) {
        int nr = min(n0w + q * 4 + reg, nN - 1);
        w4[reg] = warr[nr];
        ir4[reg] = inv_r[nr];
        is4[reg] = inv_s[nr];
    }
    float p0[4] = {0.f, 0.f, 0.f, 0.f}, p1[4] = {0.f, 0.f, 0.f, 0.f};
#pragma unroll
    for (int nt = 0; nt < 8; nt++) {
        short8 b0 = *(const short8*)(W2f + ((size_t)(nt * 2 + 0) * 64 + lane) * 8);
        short8 b1 = *(const short8*)(W2f + ((size_t)(nt * 2 + 1) * 64 + lane) * 8);
        f32x4 acc = {0.f, 0.f, 0.f, 0.f};
        acc = __builtin_amdgcn_mfma_f32_16x16x32_bf16(afr0, b0, acc, 0, 0, 0);
        acc = __builtin_amdgcn_mfma_f32_16x16x32_bf16(afr1, b1, acc, 0, 0, 0);
        int col = nt * 16 + m;
        float bc = b2l[col];
        float w30 = W3l[col * 2 + 0];
        float w31 = W3l[col * 2 + 1];
#pragma unroll
        for (int reg = 0; reg < 4; reg++) {
            float h = fmaxf((acc[reg] + w4[reg] * bc) * ir4[reg], 0.f) * is4[reg];
            p0[reg] += h * w30;
            p1[reg] += h * w31;
        }
    }
#pragma unroll
    for (int mask = 1; mask < 16; mask <<= 1) {
#pragma unroll
        for (int reg = 0; reg < 4; reg++) {
            p0[reg] += __shfl_xor(p0[reg], mask);
            p1[reg] += __shfl_xor(p1[reg], mask);
        }
    }
    if (m == 0) {
#pragma unroll
        for (int reg = 0; reg < 4; reg++) {
            int nr = n0w + q * 4 + reg;
            if (nr < nN) *(float2*)(t + (size_t)nr * 2) = make_float2(p0[reg], p1[reg]);
        }
    }
}

// ---------------- pooling (node-parallel over CSR), unroll x4 ----------------
__global__ void k_poolg(const float* __restrict__ t, const float* __restrict__ inv_r,
                        const float* __restrict__ warr, const float* __restrict__ b3,
                        const int* __restrict__ csr, const int* __restrict__ cur,
                        const int* __restrict__ degR, const int* __restrict__ batch,
                        float* out, int nN, int outSize) {
    __shared__ float sm[256];
    for (int i = threadIdx.x; i < 256; i += blockDim.x) sm[i] = 0.f;
    __syncthreads();
    float b30 = b3[0], b31 = b3[1];
    int n = blockIdx.x * blockDim.x + threadIdx.x;
    if (n < nN) {
        int deg = degR[n];
        int st = cur[n] - deg;
        float a0 = 0.f, a1 = 0.f, c0 = 0.f, c1 = 0.f;
        float d0 = 0.f, d1 = 0.f, e0 = 0.f, e1 = 0.f;
        int i = 0;
        for (; i + 4 <= deg; i += 4) {
            int sa = csr[st + i], sb = csr[st + i + 1];
            int sc = csr[st + i + 2], sd = csr[st + i + 3];
            float2 va = ((const float2*)t)[sa];
            float2 vb = ((const float2*)t)[sb];
            float2 vc = ((const float2*)t)[sc];
            float2 vd = ((const float2*)t)[sd];
            a0 += va.x; a1 += va.y;
            c0 += vb.x; c1 += vb.y;
            d0 += vc.x; d1 += vc.y;
            e0 += vd.x; e1 += vd.y;
        }
        for (; i < deg; i++) {
            float2 va = ((const float2*)t)[csr[st + i]];
            a0 += va.x; a1 += va.y;
        }
        float ir = inv_r[n];
        float wb = warr[n] * ir;
        int g = batch[n];
        atomicAdd(&sm[2 * g + 0], ((a0 + c0) + (d0 + e0)) * ir + wb * b30);
        atomicAdd(&sm[2 * g + 1], ((a1 + c1) + (d1 + e1)) * ir + wb * b31);
    }
    __syncthreads();
    for (int i = threadIdx.x; i < outSize; i += blockDim.x) atomicAdd(&out[i], sm[i]);
}

extern "C" void kernel_launch(void* const* d_in, const int* in_sizes, int n_in,
                              void* d_out, int out_size, void* d_ws, size_t ws_size,
                              hipStream_t stream) {
    const float* x     = (const float*)d_in[0];
    const int*   S     = (const int*)d_in[1];
    const int*   R     = (const int*)d_in[2];
    const int*   batch = (const int*)d_in[3];
    const float* W1 = (const float*)d_in[5];
    const float* b1 = (const float*)d_in[6];
    const float* W2 = (const float*)d_in[7];
    const float* b2 = (const float*)d_in[8];
    const float* W3 = (const float*)d_in[9];
    const float* b3 = (const float*)d_in[10];

    int nN = in_sizes[0] / 9;
    int nE = in_sizes[1];
    int nB = (nN + 255) / 256;  // 256-node buckets; requires nB <= NBMAX

    char* ws = (char*)d_ws;
    int*   cur   = (int*)ws;                          // nN
    int*   degR  = cur + nN;                          // nN
    float* inv_s = (float*)(degR + nN);               // nN
    float* inv_r = inv_s + nN;                        // nN
    float* warr  = inv_r + nN;                        // nN
    int*   gCntR = (int*)(warr + nN);                 // NBMAX
    int*   gCntS = gCntR + NBMAX;                     // NBMAX
    int*   csr   = gCntS + NBMAX;                     // nE
    bf16t* xs    = (bf16t*)(csr + nE);                // nN*16 bf16 (3.2 MB)
    bf16t* W2f   = xs + (size_t)nN * 16;              // 8192 bf16 (16 KB)
    char*  regA  = (char*)(W2f + 8192);
    // aliasing (bufR/bufS dead after k_pass2; h1s written by k_h1f afterwards)
    unsigned*      bufR = (unsigned*)regA;                                // NBMAX*BCAP*4 = 10.5 MB
    unsigned char* bufS = (unsigned char*)(bufR + (size_t)NBMAX * BCAP);  // NBMAX*BCAP   = 2.6 MB
    bf16t* h1s = (bf16t*)regA;                        // nN*64 bf16 (12.8 MB)
    float* t   = (float*)(regA + (size_t)NBMAX * BCAP * 5);  // nN*2 fp32 (past both regions)

    const int B = 256;

    // ---- build: bucket sort (512 sort blocks + 4 W2-prep blocks), then per-bucket CSR etc. ----
    hipMemsetAsync(gCntR, 0, 2 * NBMAX * 4, stream);
    k_bucket<<<516, B, 0, stream>>>(S, R, bufR, bufS, gCntR, gCntS, W2, W2f, nE, nB);
    k_pass2<<<nB, B, 0, stream>>>(bufR, bufS, gCntR, gCntS, x, csr, cur, degR,
                                  inv_r, inv_s, xs, nN, nB);

    // ---- layer 1: fused gather + 9->64 dense ----
    k_h1f<<<(nN + 15) / 16, B, 0, stream>>>((const unsigned*)xs, W1, b1, csr, cur, degR,
                                            inv_r, inv_s, h1s, warr, nN);

    // ---- layers 2+3: fused gather + MFMA 64->128->2 (also zeroes d_out) ----
    k_l2f<<<(nN + 63) / 64, B, 0, stream>>>((const unsigned*)h1s, W2f, b2, W3,
                                            inv_r, inv_s, warr, csr, cur, degR,
                                            t, (float*)d_out, out_size, nN);

    // ---- fused layer-3 aggregation + bias + pooling ----
    k_poolg<<<(nN + B - 1) / B, B, 0, stream>>>(t, inv_r, warr, b3, csr, cur, degR, batch,
                                                (float*)d_out, nN, out_size);
}